// Round 1
// 383.835 us; speedup vs baseline: 1.7031x; 1.7031x over previous
//
#include <hip/hip_runtime.h>
#include <hip/hip_bf16.h>

// PairwiseAttention: z(1,256,256,128) -> LN -> QKV -> 4-head attn (over 2nd L axis)
// -> proj + residual.  Runtime dtype sniff (fp32 vs bf16) as before.
//
// Round N: attention kernel rewritten on MFMA (v_mfma_f32_16x16x32_bf16) with
// split-bf16 (hi/lo) operands for fp32-like accuracy:
//   QKV GEMM : 3-term split (zh*wh + zh*wl + zl*wh)
//   S = QK^T : 3-term split (precision matters: exp amplifies absolute S error)
//   PV       : P bf16 (rel 2^-9, linear) x V bf16-hi (rel 2^-9, linear)
// Softmax stays fp32 on VALU. proj_res unchanged this round.

__device__ __forceinline__ float bflo(unsigned int u) { return __uint_as_float(u << 16); }
__device__ __forceinline__ float bfhi(unsigned int u) { return __uint_as_float(u & 0xffff0000u); }
__device__ __forceinline__ float bf2f(unsigned short u) { return __uint_as_float(((unsigned int)u) << 16); }
__device__ __forceinline__ unsigned short f2bf(float f) {
    unsigned int i = __float_as_uint(f);
    i += 0x7fffu + ((i >> 16) & 1u);           // round-to-nearest-even
    return (unsigned short)(i >> 16);
}
__device__ __forceinline__ void splitf(float x, unsigned short& h, unsigned short& l) {
    h = f2bf(x);
    l = f2bf(x - bf2f(h));
}

__device__ bool sniff_is_f32(const unsigned int* z) {
    int n = 0;
    for (int i = 0; i < 64; ++i) {
        float a = fabsf(bflo(z[i]));
        n += (int)(a > 1e4f) | (int)(a > 0.f && a < 1e-6f);
    }
    return n > 16;
}

template<bool F32> __device__ __forceinline__ float ldel(const void* p, int i) {
    if constexpr (F32) return ((const float*)p)[i];
    else               return bf2f(((const unsigned short*)p)[i]);
}
template<bool F32> __device__ __forceinline__ void ld8(const void* p, int i8, float* v) {
    if constexpr (F32) {
        const float4* q = (const float4*)p;
        float4 a = q[2 * i8], b = q[2 * i8 + 1];
        v[0]=a.x; v[1]=a.y; v[2]=a.z; v[3]=a.w; v[4]=b.x; v[5]=b.y; v[6]=b.z; v[7]=b.w;
    } else {
        uint4 u = ((const uint4*)p)[i8];
        const unsigned int* pu = (const unsigned int*)&u;
        #pragma unroll
        for (int j = 0; j < 4; ++j) { v[2*j] = bflo(pu[j]); v[2*j+1] = bfhi(pu[j]); }
    }
}
template<bool F32> __device__ __forceinline__ void st8(void* p, int i8, const float* v) {
    if constexpr (F32) {
        float4 a, b;
        a.x=v[0]; a.y=v[1]; a.z=v[2]; a.w=v[3];
        b.x=v[4]; b.y=v[5]; b.z=v[6]; b.w=v[7];
        ((float4*)p)[2 * i8] = a; ((float4*)p)[2 * i8 + 1] = b;
    } else {
        uint4 u; unsigned int* pu = (unsigned int*)&u;
        #pragma unroll
        for (int j = 0; j < 4; ++j)
            pu[j] = (unsigned int)f2bf(v[2*j]) | ((unsigned int)f2bf(v[2*j+1]) << 16);
        ((uint4*)p)[i8] = u;
    }
}
template<bool F32> __device__ __forceinline__ const void* elptr(const void* p, size_t off) {
    if constexpr (F32) return (const void*)((const float*)p + off);
    else               return (const void*)((const unsigned short*)p + off);
}
template<bool F32> __device__ __forceinline__ void* elptrw(void* p, size_t off) {
    if constexpr (F32) return (void*)((float*)p + off);
    else               return (void*)((unsigned short*)p + off);
}

// ---------------- MFMA plumbing ----------------
using bf16x8 = __attribute__((ext_vector_type(8))) short;   // 8 bf16 bits, 4 VGPR
using f32x4  = __attribute__((ext_vector_type(4))) float;

__device__ __forceinline__ f32x4 mfma16(bf16x8 a, bf16x8 b, f32x4 c) {
    return __builtin_amdgcn_mfma_f32_16x16x32_bf16(a, b, c, 0, 0, 0);
}

// [R][32]-bf16 LDS matrices with XOR-granule swizzle: row stride 64B, the four
// 16B granules of a row are permuted by (row>>1) so frag reads (16 lanes hit 16
// consecutive rows at one granule) spread over all 8 LDS 16B-slots -> 2-way = free.
// sw_frag(row,g)+e  ==  sw_off(row, 8*g+e)  (k-slot consistency across A and B).
__device__ __forceinline__ int sw_off (int row, int k) {
    return row * 32 + ((((k >> 3) ^ (row >> 1)) & 3) << 3) + (k & 7);
}
__device__ __forceinline__ int sw_frag(int row, int g) {
    return row * 32 + (((g ^ (row >> 1)) & 3) << 3);
}
// Vt: [32 dims][256 keys] bf16, row stride 512B, XOR key-granule by (dim&7).
__device__ __forceinline__ int vt_off(int dim, int key) {
    return dim * 256 + (key ^ ((dim & 7) << 3));
}

// ---------------- Kernel A: LN + QKV slice + MFMA flash attention per (r, h) ----------------
// grid = 1024 (r*4+h), block = 256 (4 waves; wave w owns query rows w*64..w*64+63)
template<bool F32>
__global__ __launch_bounds__(256) void attn_mfma(
    const void* __restrict__ z, const void* __restrict__ ln_g, const void* __restrict__ ln_b,
    const void* __restrict__ w_qkv, const void* __restrict__ b_qkv, void* __restrict__ out)
{
    if (sniff_is_f32((const unsigned int*)z) != F32) return;

    // 52 KB union.
    // phase1: znH[256][32] 16K | znL 16K | wtH[96][32] 6K | wtL 6K | bias[96] 384B
    // phase2: kH[256][32] 16K  | kL 16K  | vtH[32][256] 16K        | pScr 4x1K
    __shared__ __align__(16) unsigned char smem[53248];
    unsigned short* znH  = (unsigned short*)smem;
    unsigned short* znL  = (unsigned short*)(smem + 16384);
    unsigned short* wtH  = (unsigned short*)(smem + 32768);
    unsigned short* wtL  = (unsigned short*)(smem + 38912);
    float*          biasm= (float*)(smem + 45056);
    unsigned short* kHs  = znH;                                   // phase2 aliases
    unsigned short* kLs  = znL;
    unsigned short* vtH  = (unsigned short*)(smem + 32768);

    const int t    = threadIdx.x;
    const int lane = t & 63;
    const int w    = t >> 6;           // wave id 0..3
    const int g    = lane >> 4;        // 16-lane group 0..3
    const int c16  = lane & 15;
    const int r    = blockIdx.x >> 2;
    const int h    = blockIdx.x & 3;
    unsigned short* ps = (unsigned short*)(smem + 49152) + (w << 9);  // per-wave 1KB scratch

    // ---- bias_c = b_qkv[gc] + sum_k ln_b[k] * W[k][gc]  (96 threads)
    if (t < 96) {
        int gc = ((t >> 5) << 7) + (h << 5) + (t & 31);
        float b0 = 0.f, b1 = 0.f;
        #pragma unroll 8
        for (int k = 0; k < 128; k += 2) {
            b0 += ldel<F32>(ln_b, k)     * ldel<F32>(w_qkv, k * 384 + gc);
            b1 += ldel<F32>(ln_b, k + 1) * ldel<F32>(w_qkv, (k + 1) * 384 + gc);
        }
        biasm[t] = ldel<F32>(b_qkv, gc) + b0 + b1;
    }

    // ---- per-thread LN stats for row p = t (kept in registers)
    const void* zrow = elptr<F32>(z, ((size_t)r * 256 + t) << 7);
    float sum = 0.f, sumsq = 0.f;
    #pragma unroll 1
    for (int i = 0; i < 16; ++i) {
        float v[8]; ld8<F32>(zrow, i, v);
        #pragma unroll
        for (int j = 0; j < 8; ++j) { sum += v[j]; sumsq += v[j] * v[j]; }
    }
    const float mu   = sum * (1.f / 128.f);
    const float rsig = 1.0f / sqrtf(sumsq * (1.f / 128.f) - mu * mu + 1e-5f);
    const float nb   = -mu * rsig;

    __syncthreads();

    float bv[6];
    #pragma unroll
    for (int ct = 0; ct < 6; ++ct) bv[ct] = biasm[ct * 16 + c16];

    // ---- QKV GEMM: acc[qt][ct] is C-frag of rows (w*64+qt*16..+15) x cols (ct*16..+15)
    f32x4 acc[4][6];
    #pragma unroll
    for (int qt = 0; qt < 4; ++qt)
        #pragma unroll
        for (int ct = 0; ct < 6; ++ct)
            #pragma unroll
            for (int rr = 0; rr < 4; ++rr) acc[qt][ct][rr] = 0.f;

    #pragma unroll 1
    for (int kc = 0; kc < 4; ++kc) {
        // stage zn chunk: thread t = row t, 32 k-cols, hi/lo split, swizzled
        {
            float vv[8];
            #pragma unroll
            for (int i8 = 0; i8 < 4; ++i8) {
                ld8<F32>(zrow, kc * 4 + i8, vv);
                union { unsigned short s[8]; uint4 v4; } uh, ul;
                #pragma unroll
                for (int j = 0; j < 8; ++j) {
                    float zh = fmaf(vv[j], rsig, nb);
                    splitf(zh, uh.s[j], ul.s[j]);
                }
                int base = sw_frag(t, i8);
                *(uint4*)&znH[base] = uh.v4;
                *(uint4*)&znL[base] = ul.v4;
            }
        }
        // stage w' chunk transposed: [96 cols][32 k], w' = ln_g .* W-slice
        for (int idx = t; idx < 3072; idx += 256) {
            int c  = idx % 96;
            int kl = idx / 96;
            int kk = kc * 32 + kl;
            int gc = ((c >> 5) << 7) + (h << 5) + (c & 31);
            float wv = ldel<F32>(ln_g, kk) * ldel<F32>(w_qkv, kk * 384 + gc);
            unsigned short hh, ll; splitf(wv, hh, ll);
            int o = sw_off(c, kl);
            wtH[o] = hh; wtL[o] = ll;
        }
        __syncthreads();

        bf16x8 bH[6], bL[6];
        #pragma unroll
        for (int ct = 0; ct < 6; ++ct) {
            int brow = ct * 16 + c16;
            bH[ct] = *(const bf16x8*)&wtH[sw_frag(brow, g)];
            bL[ct] = *(const bf16x8*)&wtL[sw_frag(brow, g)];
        }
        #pragma unroll
        for (int qt = 0; qt < 4; ++qt) {
            int arow = (w << 6) + (qt << 4) + c16;
            bf16x8 aH = *(const bf16x8*)&znH[sw_frag(arow, g)];
            bf16x8 aL = *(const bf16x8*)&znL[sw_frag(arow, g)];
            #pragma unroll
            for (int ct = 0; ct < 6; ++ct) {
                acc[qt][ct] = mfma16(aH, bH[ct], acc[qt][ct]);
                acc[qt][ct] = mfma16(aH, bL[ct], acc[qt][ct]);
                acc[qt][ct] = mfma16(aL, bH[ct], acc[qt][ct]);
            }
        }
        __syncthreads();   // frag reads done before restage / phase2 overwrite
    }

    // ---- add bias
    #pragma unroll
    for (int qt = 0; qt < 4; ++qt)
        #pragma unroll
        for (int ct = 0; ct < 6; ++ct)
            #pragma unroll
            for (int rr = 0; rr < 4; ++rr) acc[qt][ct][rr] += bv[ct];

    // ---- redistribute K (hi/lo) and V (hi) into B-frag layouts
    #pragma unroll
    for (int qt = 0; qt < 4; ++qt) {
        #pragma unroll
        for (int rr = 0; rr < 4; ++rr) {
            int key = (w << 6) + (qt << 4) + 4 * g + rr;   // C-frag row
            unsigned short hh, ll;
            splitf(acc[qt][2][rr], hh, ll);
            kHs[sw_off(key, c16)]      = hh; kLs[sw_off(key, c16)]      = ll;
            splitf(acc[qt][3][rr], hh, ll);
            kHs[sw_off(key, 16 + c16)] = hh; kLs[sw_off(key, 16 + c16)] = ll;
            vtH[vt_off(c16,      key)] = f2bf(acc[qt][4][rr]);
            vtH[vt_off(16 + c16, key)] = f2bf(acc[qt][5][rr]);
        }
    }

    // ---- Q -> A-frags (scaled, hi/lo) via per-wave LDS bounce (wave-synchronous)
    const float SCALE = 0.17677669529663689f;   // 1/sqrt(32)
    bf16x8 qfH[4], qfL[4];
    #pragma unroll
    for (int qt = 0; qt < 4; ++qt) {
        #pragma unroll
        for (int rr = 0; rr < 4; ++rr) {
            int rw = 4 * g + rr;
            ps[sw_off(rw, c16)]      = f2bf(acc[qt][0][rr] * SCALE);
            ps[sw_off(rw, 16 + c16)] = f2bf(acc[qt][1][rr] * SCALE);
        }
        qfH[qt] = *(const bf16x8*)&ps[sw_frag(c16, g)];
        #pragma unroll
        for (int rr = 0; rr < 4; ++rr) {
            int rw = 4 * g + rr;
            float q0 = acc[qt][0][rr] * SCALE;
            float q1 = acc[qt][1][rr] * SCALE;
            ps[sw_off(rw, c16)]      = f2bf(q0 - bf2f(f2bf(q0)));
            ps[sw_off(rw, 16 + c16)] = f2bf(q1 - bf2f(f2bf(q1)));
        }
        qfL[qt] = *(const bf16x8*)&ps[sw_frag(c16, g)];
    }
    __syncthreads();   // K/V visible to all waves

    // ---- barrier-free flash loop over 8 chunks of 32 keys
    float m[16], l[16];
    #pragma unroll
    for (int i = 0; i < 16; ++i) { m[i] = -3.0e38f; l[i] = 0.f; }
    f32x4 O[4][2];
    #pragma unroll
    for (int qt = 0; qt < 4; ++qt)
        #pragma unroll
        for (int dt = 0; dt < 2; ++dt)
            #pragma unroll
            for (int rr = 0; rr < 4; ++rr) O[qt][dt][rr] = 0.f;

    f32x4 zed; zed[0] = 0.f; zed[1] = 0.f; zed[2] = 0.f; zed[3] = 0.f;

    #pragma unroll 1
    for (int kb = 0; kb < 8; ++kb) {
        int key0 = kb * 32;
        bf16x8 kfH[2], kfL[2], vf[2];
        #pragma unroll
        for (int kt = 0; kt < 2; ++kt) {
            int krow = key0 + 16 * kt + c16;
            kfH[kt] = *(const bf16x8*)&kHs[sw_frag(krow, g)];
            kfL[kt] = *(const bf16x8*)&kLs[sw_frag(krow, g)];
        }
        #pragma unroll
        for (int dt = 0; dt < 2; ++dt)
            vf[dt] = *(const bf16x8*)&vtH[vt_off(16 * dt + c16, key0 + 8 * g)];

        #pragma unroll
        for (int qt = 0; qt < 4; ++qt) {
            f32x4 s0 = mfma16(qfH[qt], kfH[0], zed);
            s0 = mfma16(qfH[qt], kfL[0], s0);
            s0 = mfma16(qfL[qt], kfH[0], s0);
            f32x4 s1 = mfma16(qfH[qt], kfH[1], zed);
            s1 = mfma16(qfH[qt], kfL[1], s1);
            s1 = mfma16(qfL[qt], kfH[1], s1);

            #pragma unroll
            for (int rr = 0; rr < 4; ++rr) {
                float mx = fmaxf(s0[rr], s1[rr]);
                mx = fmaxf(mx, __shfl_xor(mx, 1));
                mx = fmaxf(mx, __shfl_xor(mx, 2));
                mx = fmaxf(mx, __shfl_xor(mx, 4));
                mx = fmaxf(mx, __shfl_xor(mx, 8));
                const int idx = qt * 4 + rr;
                float mo = m[idx];
                float mn = fmaxf(mo, mx);
                float al = __expf(fmaxf(mo - mn, -87.f));   // safe vs -3e38 sentinel
                float p0 = __expf(s0[rr] - mn);
                float p1 = __expf(s1[rr] - mn);
                l[idx] = l[idx] * al + p0 + p1;
                m[idx] = mn;
                O[qt][0][rr] *= al;
                O[qt][1][rr] *= al;
                int rw = 4 * g + rr;
                ps[sw_off(rw, c16)]      = f2bf(p0);
                ps[sw_off(rw, 16 + c16)] = f2bf(p1);
            }
            bf16x8 pf = *(const bf16x8*)&ps[sw_frag(c16, g)];
            O[qt][0] = mfma16(pf, vf[0], O[qt][0]);
            O[qt][1] = mfma16(pf, vf[1], O[qt][1]);
        }
    }

    // ---- finalize: l is per-lane partial over this lane's 16 keys -> 16-lane reduce
    #pragma unroll
    for (int i = 0; i < 16; ++i) {
        float s = l[i];
        s += __shfl_xor(s, 1);
        s += __shfl_xor(s, 2);
        s += __shfl_xor(s, 4);
        s += __shfl_xor(s, 8);
        l[i] = s;
    }

    #pragma unroll
    for (int qt = 0; qt < 4; ++qt) {
        #pragma unroll
        for (int rr = 0; rr < 4; ++rr) {
            float rlv = 1.f / l[qt * 4 + rr];
            int grow = (r << 8) + (w << 6) + (qt << 4) + 4 * g + rr;
            size_t base = ((size_t)grow << 7) + (h << 5);
            if constexpr (F32) {
                float* po = (float*)out + base;
                po[c16]      = O[qt][0][rr] * rlv;
                po[16 + c16] = O[qt][1][rr] * rlv;
            } else {
                unsigned short* po = (unsigned short*)out + base;
                po[c16]      = f2bf(O[qt][0][rr] * rlv);
                po[16 + c16] = f2bf(O[qt][1][rr] * rlv);
            }
        }
    }
}

// ---------------- Kernel B: out = z + attnout @ w_proj + b_proj (in-place on d_out) ----------------
// grid = 4096 (16 rows each), block = 256   (unchanged this round)
template<bool F32>
__global__ __launch_bounds__(256) void proj_res(
    const void* __restrict__ z, const void* __restrict__ w_proj, const void* __restrict__ b_proj,
    void* __restrict__ out)
{
    if (sniff_is_f32((const unsigned int*)z) != F32) return;

    __shared__ unsigned int wu[8192];   // packed bf16 pairs (bf16 mode only)
    __shared__ float aT[128][20];       // [k][row] transposed a-tile, reused as out stage

    const int t = threadIdx.x;
    const size_t row0 = (size_t)blockIdx.x * 16;

    if constexpr (!F32) {
        for (int idx = t; idx < 8192; idx += 256)
            wu[idx] = ((const unsigned int*)w_proj)[idx];
    }

    {   // stage attnout tile (coalesced reads), transpose into aT
        const int rr = t >> 4;
        const int i8 = t & 15;
        float v[8];
        ld8<F32>(elptr<F32>((const void*)out, (row0 + rr) * 128), i8, v);
        #pragma unroll
        for (int j = 0; j < 8; ++j) aT[(i8 << 3) + j][rr] = v[j];
    }
    __syncthreads();

    const int c = t & 127;
    const int half = t >> 7;
    float acc8[8];
    const float bp = ldel<F32>(b_proj, c);
    #pragma unroll
    for (int rr = 0; rr < 8; ++rr) acc8[rr] = bp;

    #pragma unroll 1
    for (int k = 0; k < 128; ++k) {
        float wk;
        if constexpr (F32) {
            wk = ((const float*)w_proj)[k * 128 + c];
        } else {
            unsigned int u = wu[(k << 6) + (c >> 1)];
            wk = (c & 1) ? bfhi(u) : bflo(u);
        }
        const float4 a0 = *(const float4*)&aT[k][half * 8];
        const float4 a1 = *(const float4*)&aT[k][half * 8 + 4];
        acc8[0] = fmaf(a0.x, wk, acc8[0]);
        acc8[1] = fmaf(a0.y, wk, acc8[1]);
        acc8[2] = fmaf(a0.z, wk, acc8[2]);
        acc8[3] = fmaf(a0.w, wk, acc8[3]);
        acc8[4] = fmaf(a1.x, wk, acc8[4]);
        acc8[5] = fmaf(a1.y, wk, acc8[5]);
        acc8[6] = fmaf(a1.z, wk, acc8[6]);
        acc8[7] = fmaf(a1.w, wk, acc8[7]);
    }
    __syncthreads();
    float* ot = (float*)aT;             // reuse as [16][128] out stage
    #pragma unroll
    for (int rr = 0; rr < 8; ++rr)
        ot[(half * 8 + rr) * 128 + c] = acc8[rr];
    __syncthreads();

    {   // coalesced final write: + residual z
        const int rr = t >> 4;
        const int i8 = t & 15;
        float zv[8], v[8];
        ld8<F32>(elptr<F32>(z, (row0 + rr) * 128), i8, zv);
        const float* po = &ot[rr * 128 + (i8 << 3)];
        #pragma unroll
        for (int j = 0; j < 8; ++j) v[j] = po[j] + zv[j];
        st8<F32>(elptrw<F32>(out, (row0 + rr) * 128), i8, v);
    }
}

extern "C" void kernel_launch(void* const* d_in, const int* in_sizes, int n_in,
                              void* d_out, int out_size, void* d_ws, size_t ws_size,
                              hipStream_t stream) {
    const void* z      = d_in[0];
    const void* ln_g   = d_in[1];
    const void* ln_b   = d_in[2];
    const void* w_qkv  = d_in[3];
    const void* b_qkv  = d_in[4];
    const void* w_proj = d_in[5];
    const void* b_proj = d_in[6];
    void* out = d_out;

    attn_mfma<false><<<1024, 256, 0, stream>>>(z, ln_g, ln_b, w_qkv, b_qkv, out);
    attn_mfma<true ><<<1024, 256, 0, stream>>>(z, ln_g, ln_b, w_qkv, b_qkv, out);
    proj_res<false><<<4096, 256, 0, stream>>>(z, w_proj, b_proj, out);
    proj_res<true ><<<4096, 256, 0, stream>>>(z, w_proj, b_proj, out);
}

// Round 4
// 339.754 us; speedup vs baseline: 1.9240x; 1.1297x over previous
//
#include <hip/hip_runtime.h>
#include <hip/hip_bf16.h>

// PairwiseAttention: z(1,256,256,128) -> LN -> QKV -> 4-head attn (over 2nd L axis)
// -> proj + residual.  Runtime dtype sniff (fp32 vs bf16).
//
// Round N+3 (re-run of N+2; previous bench died on container infra, no signal):
// round-1-VERIFIED attn_mfma kept verbatim (writes attn-out to `out` in plain
// [token][128] dtype-native layout).  proj_res (serial VALU GEMM, ~150us)
// replaced by:
//   prep_wp    : split w_proj^T -> bf16 hi/lo in ws (64KB), once.
//   proj_mfma2 : in-place MFMA proj. Per-wave-disjoint token tiles, reads its
//                own 32 tokens of `out` (all reads precede all writes in wave
//                program order -> race-free), 3-term hi/lo split for fp32
//                (exact 1-term for bf16 input), fused bias+residual epilogue.
// If ws is too small: old proj_res fallback.

using ush = unsigned short;

__device__ __forceinline__ float bflo(unsigned int u) { return __uint_as_float(u << 16); }
__device__ __forceinline__ float bfhi(unsigned int u) { return __uint_as_float(u & 0xffff0000u); }
__device__ __forceinline__ float bf2f(unsigned short u) { return __uint_as_float(((unsigned int)u) << 16); }
__device__ __forceinline__ unsigned short f2bf(float f) {
    unsigned int i = __float_as_uint(f);
    i += 0x7fffu + ((i >> 16) & 1u);           // round-to-nearest-even
    return (unsigned short)(i >> 16);
}
__device__ __forceinline__ void splitf(float x, unsigned short& h, unsigned short& l) {
    h = f2bf(x);
    l = f2bf(x - bf2f(h));
}

__device__ bool sniff_is_f32(const unsigned int* z) {
    int n = 0;
    for (int i = 0; i < 64; ++i) {
        float a = fabsf(bflo(z[i]));
        n += (int)(a > 1e4f) | (int)(a > 0.f && a < 1e-6f);
    }
    return n > 16;
}

template<bool F32> __device__ __forceinline__ float ldel(const void* p, int i) {
    if constexpr (F32) return ((const float*)p)[i];
    else               return bf2f(((const unsigned short*)p)[i]);
}
template<bool F32> __device__ __forceinline__ void ld8(const void* p, int i8, float* v) {
    if constexpr (F32) {
        const float4* q = (const float4*)p;
        float4 a = q[2 * i8], b = q[2 * i8 + 1];
        v[0]=a.x; v[1]=a.y; v[2]=a.z; v[3]=a.w; v[4]=b.x; v[5]=b.y; v[6]=b.z; v[7]=b.w;
    } else {
        uint4 u = ((const uint4*)p)[i8];
        const unsigned int* pu = (const unsigned int*)&u;
        #pragma unroll
        for (int j = 0; j < 4; ++j) { v[2*j] = bflo(pu[j]); v[2*j+1] = bfhi(pu[j]); }
    }
}
template<bool F32> __device__ __forceinline__ void st8(void* p, int i8, const float* v) {
    if constexpr (F32) {
        float4 a, b;
        a.x=v[0]; a.y=v[1]; a.z=v[2]; a.w=v[3];
        b.x=v[4]; b.y=v[5]; b.z=v[6]; b.w=v[7];
        ((float4*)p)[2 * i8] = a; ((float4*)p)[2 * i8 + 1] = b;
    } else {
        uint4 u; unsigned int* pu = (unsigned int*)&u;
        #pragma unroll
        for (int j = 0; j < 4; ++j)
            pu[j] = (unsigned int)f2bf(v[2*j]) | ((unsigned int)f2bf(v[2*j+1]) << 16);
        ((uint4*)p)[i8] = u;
    }
}
template<bool F32> __device__ __forceinline__ const void* elptr(const void* p, size_t off) {
    if constexpr (F32) return (const void*)((const float*)p + off);
    else               return (const void*)((const unsigned short*)p + off);
}
template<bool F32> __device__ __forceinline__ void* elptrw(void* p, size_t off) {
    if constexpr (F32) return (void*)((float*)p + off);
    else               return (void*)((unsigned short*)p + off);
}

// ---------------- MFMA plumbing ----------------
using bf16x8 = __attribute__((ext_vector_type(8))) short;   // 8 bf16 bits, 4 VGPR
using f32x4  = __attribute__((ext_vector_type(4))) float;

__device__ __forceinline__ f32x4 mfma16(bf16x8 a, bf16x8 b, f32x4 c) {
    return __builtin_amdgcn_mfma_f32_16x16x32_bf16(a, b, c, 0, 0, 0);
}

// [R][32]-bf16 LDS matrices with XOR-granule swizzle (verified round-1):
// sw_frag(row,g)+e == sw_off(row, 8*g+e)  (slot consistency across A and B).
__device__ __forceinline__ int sw_off (int row, int k) {
    return row * 32 + ((((k >> 3) ^ (row >> 1)) & 3) << 3) + (k & 7);
}
__device__ __forceinline__ int sw_frag(int row, int g) {
    return row * 32 + (((g ^ (row >> 1)) & 3) << 3);
}
// Vt: [32 dims][256 keys] bf16, XOR key-granule by (dim&7).
__device__ __forceinline__ int vt_off(int dim, int key) {
    return dim * 256 + (key ^ ((dim & 7) << 3));
}

// ---------------- Kernel A (VERIFIED round-1): LN + QKV + MFMA flash per (r,h) ----------------
// grid = 1024 (r*4+h), block = 256 (4 waves; wave w owns query rows w*64..w*64+63)
template<bool F32>
__global__ __launch_bounds__(256) void attn_mfma(
    const void* __restrict__ z, const void* __restrict__ ln_g, const void* __restrict__ ln_b,
    const void* __restrict__ w_qkv, const void* __restrict__ b_qkv, void* __restrict__ out)
{
    if (sniff_is_f32((const unsigned int*)z) != F32) return;

    __shared__ __align__(16) unsigned char smem[53248];
    ush* znH  = (ush*)smem;
    ush* znL  = (ush*)(smem + 16384);
    ush* wtH  = (ush*)(smem + 32768);
    ush* wtL  = (ush*)(smem + 38912);
    float* biasm = (float*)(smem + 45056);
    ush* kHs  = znH;
    ush* kLs  = znL;
    ush* vtH  = (ush*)(smem + 32768);

    const int t    = threadIdx.x;
    const int lane = t & 63;
    const int w    = t >> 6;
    const int g    = lane >> 4;
    const int c16  = lane & 15;
    const int r    = blockIdx.x >> 2;
    const int h    = blockIdx.x & 3;
    ush* ps = (ush*)(smem + 49152) + (w << 9);

    if (t < 96) {
        int gc = ((t >> 5) << 7) + (h << 5) + (t & 31);
        float b0 = 0.f, b1 = 0.f;
        #pragma unroll 8
        for (int k = 0; k < 128; k += 2) {
            b0 += ldel<F32>(ln_b, k)     * ldel<F32>(w_qkv, k * 384 + gc);
            b1 += ldel<F32>(ln_b, k + 1) * ldel<F32>(w_qkv, (k + 1) * 384 + gc);
        }
        biasm[t] = ldel<F32>(b_qkv, gc) + b0 + b1;
    }

    const void* zrow = elptr<F32>(z, ((size_t)r * 256 + t) << 7);
    float sum = 0.f, sumsq = 0.f;
    #pragma unroll 1
    for (int i = 0; i < 16; ++i) {
        float v[8]; ld8<F32>(zrow, i, v);
        #pragma unroll
        for (int j = 0; j < 8; ++j) { sum += v[j]; sumsq += v[j] * v[j]; }
    }
    const float mu   = sum * (1.f / 128.f);
    const float rsig = 1.0f / sqrtf(sumsq * (1.f / 128.f) - mu * mu + 1e-5f);
    const float nb   = -mu * rsig;

    __syncthreads();

    float bv[6];
    #pragma unroll
    for (int ct = 0; ct < 6; ++ct) bv[ct] = biasm[ct * 16 + c16];

    f32x4 acc[4][6];
    #pragma unroll
    for (int qt = 0; qt < 4; ++qt)
        #pragma unroll
        for (int ct = 0; ct < 6; ++ct)
            #pragma unroll
            for (int rr = 0; rr < 4; ++rr) acc[qt][ct][rr] = 0.f;

    #pragma unroll 1
    for (int kc = 0; kc < 4; ++kc) {
        {
            float vv[8];
            #pragma unroll
            for (int i8 = 0; i8 < 4; ++i8) {
                ld8<F32>(zrow, kc * 4 + i8, vv);
                union { ush s[8]; uint4 v4; } uh, ul;
                #pragma unroll
                for (int j = 0; j < 8; ++j) {
                    float zh = fmaf(vv[j], rsig, nb);
                    splitf(zh, uh.s[j], ul.s[j]);
                }
                int b2 = sw_frag(t, i8);
                *(uint4*)&znH[b2] = uh.v4;
                *(uint4*)&znL[b2] = ul.v4;
            }
        }
        for (int idx = t; idx < 3072; idx += 256) {
            int c  = idx % 96;
            int kl = idx / 96;
            int kk = kc * 32 + kl;
            int gc = ((c >> 5) << 7) + (h << 5) + (c & 31);
            float wv = ldel<F32>(ln_g, kk) * ldel<F32>(w_qkv, kk * 384 + gc);
            ush hh, ll; splitf(wv, hh, ll);
            int o = sw_off(c, kl);
            wtH[o] = hh; wtL[o] = ll;
        }
        __syncthreads();

        bf16x8 bH[6], bL[6];
        #pragma unroll
        for (int ct = 0; ct < 6; ++ct) {
            int brow = ct * 16 + c16;
            bH[ct] = *(const bf16x8*)&wtH[sw_frag(brow, g)];
            bL[ct] = *(const bf16x8*)&wtL[sw_frag(brow, g)];
        }
        #pragma unroll
        for (int qt = 0; qt < 4; ++qt) {
            int arow = (w << 6) + (qt << 4) + c16;
            bf16x8 aHf = *(const bf16x8*)&znH[sw_frag(arow, g)];
            bf16x8 aLf = *(const bf16x8*)&znL[sw_frag(arow, g)];
            #pragma unroll
            for (int ct = 0; ct < 6; ++ct) {
                acc[qt][ct] = mfma16(aHf, bH[ct], acc[qt][ct]);
                acc[qt][ct] = mfma16(aHf, bL[ct], acc[qt][ct]);
                acc[qt][ct] = mfma16(aLf, bH[ct], acc[qt][ct]);
            }
        }
        __syncthreads();
    }

    #pragma unroll
    for (int qt = 0; qt < 4; ++qt)
        #pragma unroll
        for (int ct = 0; ct < 6; ++ct)
            #pragma unroll
            for (int rr = 0; rr < 4; ++rr) acc[qt][ct][rr] += bv[ct];

    #pragma unroll
    for (int qt = 0; qt < 4; ++qt) {
        #pragma unroll
        for (int rr = 0; rr < 4; ++rr) {
            int key = (w << 6) + (qt << 4) + 4 * g + rr;
            ush hh, ll;
            splitf(acc[qt][2][rr], hh, ll);
            kHs[sw_off(key, c16)]      = hh; kLs[sw_off(key, c16)]      = ll;
            splitf(acc[qt][3][rr], hh, ll);
            kHs[sw_off(key, 16 + c16)] = hh; kLs[sw_off(key, 16 + c16)] = ll;
            vtH[vt_off(c16,      key)] = f2bf(acc[qt][4][rr]);
            vtH[vt_off(16 + c16, key)] = f2bf(acc[qt][5][rr]);
        }
    }

    const float SCALE = 0.17677669529663689f;
    bf16x8 qfH[4], qfL[4];
    #pragma unroll
    for (int qt = 0; qt < 4; ++qt) {
        #pragma unroll
        for (int rr = 0; rr < 4; ++rr) {
            int rw = 4 * g + rr;
            ps[sw_off(rw, c16)]      = f2bf(acc[qt][0][rr] * SCALE);
            ps[sw_off(rw, 16 + c16)] = f2bf(acc[qt][1][rr] * SCALE);
        }
        qfH[qt] = *(const bf16x8*)&ps[sw_frag(c16, g)];
        #pragma unroll
        for (int rr = 0; rr < 4; ++rr) {
            int rw = 4 * g + rr;
            float q0 = acc[qt][0][rr] * SCALE;
            float q1 = acc[qt][1][rr] * SCALE;
            ps[sw_off(rw, c16)]      = f2bf(q0 - bf2f(f2bf(q0)));
            ps[sw_off(rw, 16 + c16)] = f2bf(q1 - bf2f(f2bf(q1)));
        }
        qfL[qt] = *(const bf16x8*)&ps[sw_frag(c16, g)];
    }
    __syncthreads();

    float m[16], l[16];
    #pragma unroll
    for (int i = 0; i < 16; ++i) { m[i] = -3.0e38f; l[i] = 0.f; }
    f32x4 O[4][2];
    #pragma unroll
    for (int qt = 0; qt < 4; ++qt)
        #pragma unroll
        for (int dt = 0; dt < 2; ++dt)
            #pragma unroll
            for (int rr = 0; rr < 4; ++rr) O[qt][dt][rr] = 0.f;

    f32x4 zed; zed[0] = 0.f; zed[1] = 0.f; zed[2] = 0.f; zed[3] = 0.f;

    #pragma unroll 1
    for (int kb = 0; kb < 8; ++kb) {
        int key0 = kb * 32;
        bf16x8 kfH[2], kfL[2], vf[2];
        #pragma unroll
        for (int kt = 0; kt < 2; ++kt) {
            int krow = key0 + 16 * kt + c16;
            kfH[kt] = *(const bf16x8*)&kHs[sw_frag(krow, g)];
            kfL[kt] = *(const bf16x8*)&kLs[sw_frag(krow, g)];
        }
        #pragma unroll
        for (int dt = 0; dt < 2; ++dt)
            vf[dt] = *(const bf16x8*)&vtH[vt_off(16 * dt + c16, key0 + 8 * g)];

        #pragma unroll
        for (int qt = 0; qt < 4; ++qt) {
            f32x4 s0 = mfma16(qfH[qt], kfH[0], zed);
            s0 = mfma16(qfH[qt], kfL[0], s0);
            s0 = mfma16(qfL[qt], kfH[0], s0);
            f32x4 s1 = mfma16(qfH[qt], kfH[1], zed);
            s1 = mfma16(qfH[qt], kfL[1], s1);
            s1 = mfma16(qfL[qt], kfH[1], s1);

            #pragma unroll
            for (int rr = 0; rr < 4; ++rr) {
                float mx = fmaxf(s0[rr], s1[rr]);
                mx = fmaxf(mx, __shfl_xor(mx, 1));
                mx = fmaxf(mx, __shfl_xor(mx, 2));
                mx = fmaxf(mx, __shfl_xor(mx, 4));
                mx = fmaxf(mx, __shfl_xor(mx, 8));
                const int idx = qt * 4 + rr;
                float mo = m[idx];
                float mn = fmaxf(mo, mx);
                float al = __expf(fmaxf(mo - mn, -87.f));
                float p0 = __expf(s0[rr] - mn);
                float p1 = __expf(s1[rr] - mn);
                l[idx] = l[idx] * al + p0 + p1;
                m[idx] = mn;
                O[qt][0][rr] *= al;
                O[qt][1][rr] *= al;
                int rw = 4 * g + rr;
                ps[sw_off(rw, c16)]      = f2bf(p0);
                ps[sw_off(rw, 16 + c16)] = f2bf(p1);
            }
            bf16x8 pf = *(const bf16x8*)&ps[sw_frag(c16, g)];
            O[qt][0] = mfma16(pf, vf[0], O[qt][0]);
            O[qt][1] = mfma16(pf, vf[1], O[qt][1]);
        }
    }

    #pragma unroll
    for (int i = 0; i < 16; ++i) {
        float s = l[i];
        s += __shfl_xor(s, 1);
        s += __shfl_xor(s, 2);
        s += __shfl_xor(s, 4);
        s += __shfl_xor(s, 8);
        l[i] = s;
    }

    #pragma unroll
    for (int qt = 0; qt < 4; ++qt) {
        #pragma unroll
        for (int rr = 0; rr < 4; ++rr) {
            float rlv = 1.f / l[qt * 4 + rr];
            int grow = (r << 8) + (w << 6) + (qt << 4) + 4 * g + rr;
            size_t base = ((size_t)grow << 7) + (h << 5);
            if constexpr (F32) {
                float* po = (float*)out + base;
                po[c16]      = O[qt][0][rr] * rlv;
                po[16 + c16] = O[qt][1][rr] * rlv;
            } else {
                ush* po = (ush*)out + base;
                po[c16]      = f2bf(O[qt][0][rr] * rlv);
                po[16 + c16] = f2bf(O[qt][1][rr] * rlv);
            }
        }
    }
}

// ---------------- prep_wp: split w_proj^T -> bf16 hi/lo (grid 32 x 256) ----------------
// wpT layout: wp[c*128 + k] = w_proj[k][c]
template<bool F32>
__global__ __launch_bounds__(256) void prep_wp(
    const void* __restrict__ z, const void* __restrict__ w_proj,
    ush* __restrict__ wpH, ush* __restrict__ wpL)
{
    if (sniff_is_f32((const unsigned int*)z) != F32) return;
    const int gid = blockIdx.x * 256 + threadIdx.x;
    for (int e = gid; e < 16384; e += 32 * 256) {
        int c = e >> 7, k = e & 127;
        float v = ldel<F32>(w_proj, k * 128 + c);
        ush hh, ll; splitf(v, hh, ll);
        wpH[e] = hh; wpL[e] = ll;
    }
}

// ---------------- proj_mfma2: out = z + out @ w_proj + b_proj (in-place MFMA) ----------------
// grid 512 (128 tokens), block 256 (4 waves x 32 tokens, per-wave disjoint).
// A = wpT rows (out cols, M), B = attn-out rows (tokens, N), read directly from
// `out` with in-register hi/lo split. All reads precede all writes in wave
// program order and waves touch disjoint tokens -> in-place safe, zero LDS.
// C row = out-col (4 contiguous per lane) -> vectorized residual epilogue.
template<bool F32>
__global__ __launch_bounds__(256) void proj_mfma2(
    const void* __restrict__ z, const void* __restrict__ b_proj,
    const ush* __restrict__ wpH, const ush* __restrict__ wpL,
    void* __restrict__ out)
{
    if (sniff_is_f32((const unsigned int*)z) != F32) return;

    const int t    = threadIdx.x;
    const int lane = t & 63;
    const int w    = t >> 6;
    const int g    = lane >> 4;
    const int c16  = lane & 15;
    const int tok0 = blockIdx.x * 128 + w * 32;

    f32x4 acc[8][2];
    #pragma unroll
    for (int at = 0; at < 8; ++at)
        #pragma unroll
        for (int bt = 0; bt < 2; ++bt)
            #pragma unroll
            for (int rr = 0; rr < 4; ++rr) acc[at][bt][rr] = 0.f;

    #pragma unroll 1
    for (int kc = 0; kc < 4; ++kc) {
        // B-frags: lane (g,c16) needs a[token = tile+c16][k = kc*32 + 8g + e]
        bf16x8 btH[2], btL[2];
        #pragma unroll
        for (int bt = 0; bt < 2; ++bt) {
            const int token = tok0 + bt * 16 + c16;
            float av[8];
            ld8<F32>(elptr<F32>((const void*)out, (size_t)token * 128 + kc * 32 + 8 * g), 0, av);
            union { ush s[8]; bf16x8 v; } hU, lU;
            #pragma unroll
            for (int j = 0; j < 8; ++j) splitf(av[j], hU.s[j], lU.s[j]);
            btH[bt] = hU.v; btL[bt] = lU.v;
        }
        #pragma unroll
        for (int at = 0; at < 8; ++at) {
            const size_t wrow = (size_t)(at * 16 + c16) * 128 + kc * 32 + 8 * g;
            bf16x8 awH = *(const bf16x8*)&wpH[wrow];
            #pragma unroll
            for (int bt = 0; bt < 2; ++bt)
                acc[at][bt] = mfma16(awH, btH[bt], acc[at][bt]);
            if constexpr (F32) {
                bf16x8 awL = *(const bf16x8*)&wpL[wrow];
                #pragma unroll
                for (int bt = 0; bt < 2; ++bt) {
                    acc[at][bt] = mfma16(awH, btL[bt], acc[at][bt]);
                    acc[at][bt] = mfma16(awL, btH[bt], acc[at][bt]);
                }
            }
        }
    }

    #pragma unroll
    for (int at = 0; at < 8; ++at) {
        const int c0 = at * 16 + 4 * g;
        float bp[4];
        #pragma unroll
        for (int rr = 0; rr < 4; ++rr) bp[rr] = ldel<F32>(b_proj, c0 + rr);
        #pragma unroll
        for (int bt = 0; bt < 2; ++bt) {
            const int n = tok0 + bt * 16 + c16;
            const size_t ob = (size_t)n * 128 + c0;
            if constexpr (F32) {
                const float4 zv = *(const float4*)((const float*)z + ob);
                float4 o;
                o.x = acc[at][bt][0] + bp[0] + zv.x;
                o.y = acc[at][bt][1] + bp[1] + zv.y;
                o.z = acc[at][bt][2] + bp[2] + zv.z;
                o.w = acc[at][bt][3] + bp[3] + zv.w;
                *(float4*)((float*)out + ob) = o;
            } else {
                const uint2 zu = *(const uint2*)((const ush*)z + ob);
                float v0 = acc[at][bt][0] + bp[0] + bflo(zu.x);
                float v1 = acc[at][bt][1] + bp[1] + bfhi(zu.x);
                float v2 = acc[at][bt][2] + bp[2] + bflo(zu.y);
                float v3 = acc[at][bt][3] + bp[3] + bfhi(zu.y);
                uint2 u;
                u.x = (unsigned int)f2bf(v0) | ((unsigned int)f2bf(v1) << 16);
                u.y = (unsigned int)f2bf(v2) | ((unsigned int)f2bf(v3) << 16);
                *(uint2*)((ush*)out + ob) = u;
            }
        }
    }
}

// ---------------- proj_res fallback (ws too small; verified round-0/1) ----------------
template<bool F32>
__global__ __launch_bounds__(256) void proj_res(
    const void* __restrict__ z, const void* __restrict__ w_proj, const void* __restrict__ b_proj,
    void* __restrict__ out)
{
    if (sniff_is_f32((const unsigned int*)z) != F32) return;

    __shared__ unsigned int wu[8192];
    __shared__ float aT[128][20];

    const int t = threadIdx.x;
    const size_t row0 = (size_t)blockIdx.x * 16;

    if constexpr (!F32) {
        for (int idx = t; idx < 8192; idx += 256)
            wu[idx] = ((const unsigned int*)w_proj)[idx];
    }

    {
        const int rr = t >> 4;
        const int i8 = t & 15;
        float v[8];
        ld8<F32>(elptr<F32>((const void*)out, (row0 + rr) * 128), i8, v);
        #pragma unroll
        for (int j = 0; j < 8; ++j) aT[(i8 << 3) + j][rr] = v[j];
    }
    __syncthreads();

    const int c = t & 127;
    const int half = t >> 7;
    float acc8[8];
    const float bp = ldel<F32>(b_proj, c);
    #pragma unroll
    for (int rr = 0; rr < 8; ++rr) acc8[rr] = bp;

    #pragma unroll 1
    for (int k = 0; k < 128; ++k) {
        float wk;
        if constexpr (F32) {
            wk = ((const float*)w_proj)[k * 128 + c];
        } else {
            unsigned int u = wu[(k << 6) + (c >> 1)];
            wk = (c & 1) ? bfhi(u) : bflo(u);
        }
        const float4 a0 = *(const float4*)&aT[k][half * 8];
        const float4 a1 = *(const float4*)&aT[k][half * 8 + 4];
        acc8[0] = fmaf(a0.x, wk, acc8[0]);
        acc8[1] = fmaf(a0.y, wk, acc8[1]);
        acc8[2] = fmaf(a0.z, wk, acc8[2]);
        acc8[3] = fmaf(a0.w, wk, acc8[3]);
        acc8[4] = fmaf(a1.x, wk, acc8[4]);
        acc8[5] = fmaf(a1.y, wk, acc8[5]);
        acc8[6] = fmaf(a1.z, wk, acc8[6]);
        acc8[7] = fmaf(a1.w, wk, acc8[7]);
    }
    __syncthreads();
    float* ot = (float*)aT;
    #pragma unroll
    for (int rr = 0; rr < 8; ++rr)
        ot[(half * 8 + rr) * 128 + c] = acc8[rr];
    __syncthreads();

    {
        const int rr = t >> 4;
        const int i8 = t & 15;
        float zv[8], v[8];
        ld8<F32>(elptr<F32>(z, (row0 + rr) * 128), i8, zv);
        const float* po = &ot[rr * 128 + (i8 << 3)];
        #pragma unroll
        for (int j = 0; j < 8; ++j) v[j] = po[j] + zv[j];
        st8<F32>(elptrw<F32>(out, (row0 + rr) * 128), i8, v);
    }
}

extern "C" void kernel_launch(void* const* d_in, const int* in_sizes, int n_in,
                              void* d_out, int out_size, void* d_ws, size_t ws_size,
                              hipStream_t stream) {
    const void* z      = d_in[0];
    const void* ln_g   = d_in[1];
    const void* ln_b   = d_in[2];
    const void* w_qkv  = d_in[3];
    const void* b_qkv  = d_in[4];
    const void* w_proj = d_in[5];
    const void* b_proj = d_in[6];
    void* out = d_out;

    attn_mfma<false><<<1024, 256, 0, stream>>>(z, ln_g, ln_b, w_qkv, b_qkv, out);
    attn_mfma<true ><<<1024, 256, 0, stream>>>(z, ln_g, ln_b, w_qkv, b_qkv, out);

    if (ws_size >= 65536 && d_ws != nullptr) {
        ush* wpH = (ush*)d_ws;
        ush* wpL = wpH + 16384;
        prep_wp<false><<<32, 256, 0, stream>>>(z, w_proj, wpH, wpL);
        prep_wp<true ><<<32, 256, 0, stream>>>(z, w_proj, wpH, wpL);
        proj_mfma2<false><<<512, 256, 0, stream>>>(z, b_proj, wpH, wpL, out);
        proj_mfma2<true ><<<512, 256, 0, stream>>>(z, b_proj, wpH, wpL, out);
    } else {
        proj_res<false><<<4096, 256, 0, stream>>>(z, w_proj, b_proj, out);
        proj_res<true ><<<4096, 256, 0, stream>>>(z, w_proj, b_proj, out);
    }
}

// Round 5
// 293.087 us; speedup vs baseline: 2.2304x; 1.1592x over previous
//
#include <hip/hip_runtime.h>
#include <hip/hip_bf16.h>

// PairwiseAttention: z(1,256,256,128) -> LN -> QKV -> 4-head attn (over 2nd L axis)
// -> proj + residual.  Runtime dtype sniff (fp32 vs bf16).
//
// Round N+4: attack attn_mfma's redundant per-block weight work (70MB fetch,
// 12K scalar loads + 6K splitf + 128-iter bias loop PER BLOCK x1024):
//   prep_w    : (validated machinery) computes ONCE: the byte-identical
//               swizzled w' LDS images (hi/lo) per (h,kc), biasG, and w_proj^T
//               hi/lo for proj.  attn copies its tile linearly (uint4).
//   attn_mfma2: round-1-verified attn with ONLY the staging source changed
//               (LDS bytes provably identical; flash/MFMA untouched).
//   proj_mfma2: unchanged from round 4 (validated).
// Fallback to round-1 attn_mfma + proj_res when ws is too small.

using ush = unsigned short;

__device__ __forceinline__ float bflo(unsigned int u) { return __uint_as_float(u << 16); }
__device__ __forceinline__ float bfhi(unsigned int u) { return __uint_as_float(u & 0xffff0000u); }
__device__ __forceinline__ float bf2f(unsigned short u) { return __uint_as_float(((unsigned int)u) << 16); }
__device__ __forceinline__ unsigned short f2bf(float f) {
    unsigned int i = __float_as_uint(f);
    i += 0x7fffu + ((i >> 16) & 1u);           // round-to-nearest-even
    return (unsigned short)(i >> 16);
}
__device__ __forceinline__ void splitf(float x, unsigned short& h, unsigned short& l) {
    h = f2bf(x);
    l = f2bf(x - bf2f(h));
}

__device__ bool sniff_is_f32(const unsigned int* z) {
    int n = 0;
    for (int i = 0; i < 64; ++i) {
        float a = fabsf(bflo(z[i]));
        n += (int)(a > 1e4f) | (int)(a > 0.f && a < 1e-6f);
    }
    return n > 16;
}

template<bool F32> __device__ __forceinline__ float ldel(const void* p, int i) {
    if constexpr (F32) return ((const float*)p)[i];
    else               return bf2f(((const unsigned short*)p)[i]);
}
template<bool F32> __device__ __forceinline__ void ld8(const void* p, int i8, float* v) {
    if constexpr (F32) {
        const float4* q = (const float4*)p;
        float4 a = q[2 * i8], b = q[2 * i8 + 1];
        v[0]=a.x; v[1]=a.y; v[2]=a.z; v[3]=a.w; v[4]=b.x; v[5]=b.y; v[6]=b.z; v[7]=b.w;
    } else {
        uint4 u = ((const uint4*)p)[i8];
        const unsigned int* pu = (const unsigned int*)&u;
        #pragma unroll
        for (int j = 0; j < 4; ++j) { v[2*j] = bflo(pu[j]); v[2*j+1] = bfhi(pu[j]); }
    }
}
template<bool F32> __device__ __forceinline__ void st8(void* p, int i8, const float* v) {
    if constexpr (F32) {
        float4 a, b;
        a.x=v[0]; a.y=v[1]; a.z=v[2]; a.w=v[3];
        b.x=v[4]; b.y=v[5]; b.z=v[6]; b.w=v[7];
        ((float4*)p)[2 * i8] = a; ((float4*)p)[2 * i8 + 1] = b;
    } else {
        uint4 u; unsigned int* pu = (unsigned int*)&u;
        #pragma unroll
        for (int j = 0; j < 4; ++j)
            pu[j] = (unsigned int)f2bf(v[2*j]) | ((unsigned int)f2bf(v[2*j+1]) << 16);
        ((uint4*)p)[i8] = u;
    }
}
template<bool F32> __device__ __forceinline__ const void* elptr(const void* p, size_t off) {
    if constexpr (F32) return (const void*)((const float*)p + off);
    else               return (const void*)((const unsigned short*)p + off);
}
template<bool F32> __device__ __forceinline__ void* elptrw(void* p, size_t off) {
    if constexpr (F32) return (void*)((float*)p + off);
    else               return (void*)((unsigned short*)p + off);
}

// ---------------- MFMA plumbing ----------------
using bf16x8 = __attribute__((ext_vector_type(8))) short;   // 8 bf16 bits, 4 VGPR
using f32x4  = __attribute__((ext_vector_type(4))) float;

__device__ __forceinline__ f32x4 mfma16(bf16x8 a, bf16x8 b, f32x4 c) {
    return __builtin_amdgcn_mfma_f32_16x16x32_bf16(a, b, c, 0, 0, 0);
}

// [R][32]-bf16 LDS matrices with XOR-granule swizzle (verified round-1):
// sw_frag(row,g)+e == sw_off(row, 8*g+e)  (slot consistency across A and B).
__device__ __forceinline__ int sw_off (int row, int k) {
    return row * 32 + ((((k >> 3) ^ (row >> 1)) & 3) << 3) + (k & 7);
}
__device__ __forceinline__ int sw_frag(int row, int g) {
    return row * 32 + (((g ^ (row >> 1)) & 3) << 3);
}
// Vt: [32 dims][256 keys] bf16, XOR key-granule by (dim&7).
__device__ __forceinline__ int vt_off(int dim, int key) {
    return dim * 256 + (key ^ ((dim & 7) << 3));
}

// ws layout (bytes):
//   wqSH 0       (98304)   swizzled w' hi images: [(h*4+kc)*3072 + sw_off(c,kl)]
//   wqSL 98304   (98304)
//   wpH  196608  (32768)   w_proj^T hi: [c*128+k]
//   wpL  229376  (32768)
//   biasG 262144 (1536)    float[4][96]
#define WS_NEED 263680ull

// ---------------- prep_w: all weight preprocessing, once (grid 64 x 256) ----------------
template<bool F32>
__global__ __launch_bounds__(256) void prep_w(
    const void* __restrict__ z, const void* __restrict__ ln_g, const void* __restrict__ ln_b,
    const void* __restrict__ w_qkv, const void* __restrict__ b_qkv, const void* __restrict__ w_proj,
    ush* __restrict__ wqSH, ush* __restrict__ wqSL,
    ush* __restrict__ wpH, ush* __restrict__ wpL, float* __restrict__ biasG)
{
    if (sniff_is_f32((const unsigned int*)z) != F32) return;
    const int gid = blockIdx.x * 256 + threadIdx.x;
    const int NT  = 64 * 256;

    // swizzled g.*W_qkv images: e = (h*4+kc)*3072 + c*32 + kl
    for (int e = gid; e < 49152; e += NT) {
        int kl = e & 31;
        int c  = (e >> 5) % 96;
        int hk = e / 3072;            // h*4+kc
        int h  = hk >> 2, kc = hk & 3;
        int k  = kc * 32 + kl;
        int gc = ((c >> 5) << 7) + (h << 5) + (c & 31);
        float wv = ldel<F32>(ln_g, k) * ldel<F32>(w_qkv, k * 384 + gc);
        ush hh, ll; splitf(wv, hh, ll);
        int o = hk * 3072 + sw_off(c, kl);   // same index expression as round-1 in-kernel stage
        wqSH[o] = hh; wqSL[o] = ll;
    }
    // w_proj transposed hi/lo: wp[c*128+k] = w_proj[k][c]
    for (int e = gid; e < 16384; e += NT) {
        int c = e >> 7, k = e & 127;
        float v = ldel<F32>(w_proj, k * 128 + c);
        ush hh, ll; splitf(v, hh, ll);
        wpH[e] = hh; wpL[e] = ll;
    }
    // bias_c = b_qkv[gc] + sum_k ln_b[k] * W[k][gc]   (exact round-1 loop, once per head)
    if (blockIdx.x < 4 && threadIdx.x < 96) {
        int h = blockIdx.x, c = threadIdx.x;
        int gc = ((c >> 5) << 7) + (h << 5) + (c & 31);
        float b0 = 0.f, b1 = 0.f;
        #pragma unroll 8
        for (int k = 0; k < 128; k += 2) {
            b0 += ldel<F32>(ln_b, k)     * ldel<F32>(w_qkv, k * 384 + gc);
            b1 += ldel<F32>(ln_b, k + 1) * ldel<F32>(w_qkv, (k + 1) * 384 + gc);
        }
        biasG[h * 96 + c] = ldel<F32>(b_qkv, gc) + b0 + b1;
    }
}

// ---------------- attn_mfma2: round-1-verified attn, staging from prepped ws ----------------
// grid = 1024 (r*4+h), block = 256 (4 waves; wave w owns query rows w*64..w*64+63)
template<bool F32>
__global__ __launch_bounds__(256) void attn_mfma2(
    const void* __restrict__ z, const ush* __restrict__ wqSH, const ush* __restrict__ wqSL,
    const float* __restrict__ biasG, void* __restrict__ out)
{
    if (sniff_is_f32((const unsigned int*)z) != F32) return;

    __shared__ __align__(16) unsigned char smem[53248];
    ush* znH  = (ush*)smem;
    ush* znL  = (ush*)(smem + 16384);
    ush* wtH  = (ush*)(smem + 32768);
    ush* wtL  = (ush*)(smem + 38912);
    ush* kHs  = znH;
    ush* kLs  = znL;
    ush* vtH  = (ush*)(smem + 32768);

    const int t    = threadIdx.x;
    const int lane = t & 63;
    const int w    = t >> 6;
    const int g    = lane >> 4;
    const int c16  = lane & 15;
    const int r    = blockIdx.x >> 2;
    const int h    = blockIdx.x & 3;
    ush* ps = (ush*)(smem + 49152) + (w << 9);

    const void* zrow = elptr<F32>(z, ((size_t)r * 256 + t) << 7);
    float sum = 0.f, sumsq = 0.f;
    #pragma unroll 1
    for (int i = 0; i < 16; ++i) {
        float v[8]; ld8<F32>(zrow, i, v);
        #pragma unroll
        for (int j = 0; j < 8; ++j) { sum += v[j]; sumsq += v[j] * v[j]; }
    }
    const float mu   = sum * (1.f / 128.f);
    const float rsig = 1.0f / sqrtf(sumsq * (1.f / 128.f) - mu * mu + 1e-5f);
    const float nb   = -mu * rsig;

    float bv[6];
    #pragma unroll
    for (int ct = 0; ct < 6; ++ct) bv[ct] = biasG[h * 96 + ct * 16 + c16];

    f32x4 acc[4][6];
    #pragma unroll
    for (int qt = 0; qt < 4; ++qt)
        #pragma unroll
        for (int ct = 0; ct < 6; ++ct)
            #pragma unroll
            for (int rr = 0; rr < 4; ++rr) acc[qt][ct][rr] = 0.f;

    #pragma unroll 1
    for (int kc = 0; kc < 4; ++kc) {
        {   // stage zn chunk (hi/lo split, swizzled) — identical to round 1
            float vv[8];
            #pragma unroll
            for (int i8 = 0; i8 < 4; ++i8) {
                ld8<F32>(zrow, kc * 4 + i8, vv);
                union { ush s[8]; uint4 v4; } uh, ul;
                #pragma unroll
                for (int j = 0; j < 8; ++j) {
                    float zh = fmaf(vv[j], rsig, nb);
                    splitf(zh, uh.s[j], ul.s[j]);
                }
                int b2 = sw_frag(t, i8);
                *(uint4*)&znH[b2] = uh.v4;
                *(uint4*)&znL[b2] = ul.v4;
            }
        }
        {   // stage w' chunk: LINEAR copy of prepped swizzled image (byte-identical LDS)
            const uint4* srcH = (const uint4*)(wqSH + (h * 4 + kc) * 3072);
            const uint4* srcL = (const uint4*)(wqSL + (h * 4 + kc) * 3072);
            #pragma unroll
            for (int i = t; i < 768; i += 256) {
                if (i < 384) ((uint4*)wtH)[i]       = srcH[i];
                else         ((uint4*)wtL)[i - 384] = srcL[i - 384];
            }
        }
        __syncthreads();

        bf16x8 bH[6], bL[6];
        #pragma unroll
        for (int ct = 0; ct < 6; ++ct) {
            int brow = ct * 16 + c16;
            bH[ct] = *(const bf16x8*)&wtH[sw_frag(brow, g)];
            bL[ct] = *(const bf16x8*)&wtL[sw_frag(brow, g)];
        }
        #pragma unroll
        for (int qt = 0; qt < 4; ++qt) {
            int arow = (w << 6) + (qt << 4) + c16;
            bf16x8 aHf = *(const bf16x8*)&znH[sw_frag(arow, g)];
            bf16x8 aLf = *(const bf16x8*)&znL[sw_frag(arow, g)];
            #pragma unroll
            for (int ct = 0; ct < 6; ++ct) {
                acc[qt][ct] = mfma16(aHf, bH[ct], acc[qt][ct]);
                acc[qt][ct] = mfma16(aHf, bL[ct], acc[qt][ct]);
                acc[qt][ct] = mfma16(aLf, bH[ct], acc[qt][ct]);
            }
        }
        __syncthreads();
    }

    #pragma unroll
    for (int qt = 0; qt < 4; ++qt)
        #pragma unroll
        for (int ct = 0; ct < 6; ++ct)
            #pragma unroll
            for (int rr = 0; rr < 4; ++rr) acc[qt][ct][rr] += bv[ct];

    #pragma unroll
    for (int qt = 0; qt < 4; ++qt) {
        #pragma unroll
        for (int rr = 0; rr < 4; ++rr) {
            int key = (w << 6) + (qt << 4) + 4 * g + rr;
            ush hh, ll;
            splitf(acc[qt][2][rr], hh, ll);
            kHs[sw_off(key, c16)]      = hh; kLs[sw_off(key, c16)]      = ll;
            splitf(acc[qt][3][rr], hh, ll);
            kHs[sw_off(key, 16 + c16)] = hh; kLs[sw_off(key, 16 + c16)] = ll;
            vtH[vt_off(c16,      key)] = f2bf(acc[qt][4][rr]);
            vtH[vt_off(16 + c16, key)] = f2bf(acc[qt][5][rr]);
        }
    }

    const float SCALE = 0.17677669529663689f;
    bf16x8 qfH[4], qfL[4];
    #pragma unroll
    for (int qt = 0; qt < 4; ++qt) {
        #pragma unroll
        for (int rr = 0; rr < 4; ++rr) {
            int rw = 4 * g + rr;
            ps[sw_off(rw, c16)]      = f2bf(acc[qt][0][rr] * SCALE);
            ps[sw_off(rw, 16 + c16)] = f2bf(acc[qt][1][rr] * SCALE);
        }
        qfH[qt] = *(const bf16x8*)&ps[sw_frag(c16, g)];
        #pragma unroll
        for (int rr = 0; rr < 4; ++rr) {
            int rw = 4 * g + rr;
            float q0 = acc[qt][0][rr] * SCALE;
            float q1 = acc[qt][1][rr] * SCALE;
            ps[sw_off(rw, c16)]      = f2bf(q0 - bf2f(f2bf(q0)));
            ps[sw_off(rw, 16 + c16)] = f2bf(q1 - bf2f(f2bf(q1)));
        }
        qfL[qt] = *(const bf16x8*)&ps[sw_frag(c16, g)];
    }
    __syncthreads();

    float m[16], l[16];
    #pragma unroll
    for (int i = 0; i < 16; ++i) { m[i] = -3.0e38f; l[i] = 0.f; }
    f32x4 O[4][2];
    #pragma unroll
    for (int qt = 0; qt < 4; ++qt)
        #pragma unroll
        for (int dt = 0; dt < 2; ++dt)
            #pragma unroll
            for (int rr = 0; rr < 4; ++rr) O[qt][dt][rr] = 0.f;

    f32x4 zed; zed[0] = 0.f; zed[1] = 0.f; zed[2] = 0.f; zed[3] = 0.f;

    #pragma unroll 1
    for (int kb = 0; kb < 8; ++kb) {
        int key0 = kb * 32;
        bf16x8 kfH[2], kfL[2], vf[2];
        #pragma unroll
        for (int kt = 0; kt < 2; ++kt) {
            int krow = key0 + 16 * kt + c16;
            kfH[kt] = *(const bf16x8*)&kHs[sw_frag(krow, g)];
            kfL[kt] = *(const bf16x8*)&kLs[sw_frag(krow, g)];
        }
        #pragma unroll
        for (int dt = 0; dt < 2; ++dt)
            vf[dt] = *(const bf16x8*)&vtH[vt_off(16 * dt + c16, key0 + 8 * g)];

        #pragma unroll
        for (int qt = 0; qt < 4; ++qt) {
            f32x4 s0 = mfma16(qfH[qt], kfH[0], zed);
            s0 = mfma16(qfH[qt], kfL[0], s0);
            s0 = mfma16(qfL[qt], kfH[0], s0);
            f32x4 s1 = mfma16(qfH[qt], kfH[1], zed);
            s1 = mfma16(qfH[qt], kfL[1], s1);
            s1 = mfma16(qfL[qt], kfH[1], s1);

            #pragma unroll
            for (int rr = 0; rr < 4; ++rr) {
                float mx = fmaxf(s0[rr], s1[rr]);
                mx = fmaxf(mx, __shfl_xor(mx, 1));
                mx = fmaxf(mx, __shfl_xor(mx, 2));
                mx = fmaxf(mx, __shfl_xor(mx, 4));
                mx = fmaxf(mx, __shfl_xor(mx, 8));
                const int idx = qt * 4 + rr;
                float mo = m[idx];
                float mn = fmaxf(mo, mx);
                float al = __expf(fmaxf(mo - mn, -87.f));
                float p0 = __expf(s0[rr] - mn);
                float p1 = __expf(s1[rr] - mn);
                l[idx] = l[idx] * al + p0 + p1;
                m[idx] = mn;
                O[qt][0][rr] *= al;
                O[qt][1][rr] *= al;
                int rw = 4 * g + rr;
                ps[sw_off(rw, c16)]      = f2bf(p0);
                ps[sw_off(rw, 16 + c16)] = f2bf(p1);
            }
            bf16x8 pf = *(const bf16x8*)&ps[sw_frag(c16, g)];
            O[qt][0] = mfma16(pf, vf[0], O[qt][0]);
            O[qt][1] = mfma16(pf, vf[1], O[qt][1]);
        }
    }

    #pragma unroll
    for (int i = 0; i < 16; ++i) {
        float s = l[i];
        s += __shfl_xor(s, 1);
        s += __shfl_xor(s, 2);
        s += __shfl_xor(s, 4);
        s += __shfl_xor(s, 8);
        l[i] = s;
    }

    #pragma unroll
    for (int qt = 0; qt < 4; ++qt) {
        #pragma unroll
        for (int rr = 0; rr < 4; ++rr) {
            float rlv = 1.f / l[qt * 4 + rr];
            int grow = (r << 8) + (w << 6) + (qt << 4) + 4 * g + rr;
            size_t base = ((size_t)grow << 7) + (h << 5);
            if constexpr (F32) {
                float* po = (float*)out + base;
                po[c16]      = O[qt][0][rr] * rlv;
                po[16 + c16] = O[qt][1][rr] * rlv;
            } else {
                ush* po = (ush*)out + base;
                po[c16]      = f2bf(O[qt][0][rr] * rlv);
                po[16 + c16] = f2bf(O[qt][1][rr] * rlv);
            }
        }
    }
}

// ---------------- proj_mfma2: out = z + out @ w_proj + b_proj (in-place MFMA, validated) ----------------
template<bool F32>
__global__ __launch_bounds__(256) void proj_mfma2(
    const void* __restrict__ z, const void* __restrict__ b_proj,
    const ush* __restrict__ wpH, const ush* __restrict__ wpL,
    void* __restrict__ out)
{
    if (sniff_is_f32((const unsigned int*)z) != F32) return;

    const int t    = threadIdx.x;
    const int lane = t & 63;
    const int w    = t >> 6;
    const int g    = lane >> 4;
    const int c16  = lane & 15;
    const int tok0 = blockIdx.x * 128 + w * 32;

    f32x4 acc[8][2];
    #pragma unroll
    for (int at = 0; at < 8; ++at)
        #pragma unroll
        for (int bt = 0; bt < 2; ++bt)
            #pragma unroll
            for (int rr = 0; rr < 4; ++rr) acc[at][bt][rr] = 0.f;

    #pragma unroll 1
    for (int kc = 0; kc < 4; ++kc) {
        bf16x8 btH[2], btL[2];
        #pragma unroll
        for (int bt = 0; bt < 2; ++bt) {
            const int token = tok0 + bt * 16 + c16;
            float av[8];
            ld8<F32>(elptr<F32>((const void*)out, (size_t)token * 128 + kc * 32 + 8 * g), 0, av);
            union { ush s[8]; bf16x8 v; } hU, lU;
            #pragma unroll
            for (int j = 0; j < 8; ++j) splitf(av[j], hU.s[j], lU.s[j]);
            btH[bt] = hU.v; btL[bt] = lU.v;
        }
        #pragma unroll
        for (int at = 0; at < 8; ++at) {
            const size_t wrow = (size_t)(at * 16 + c16) * 128 + kc * 32 + 8 * g;
            bf16x8 awH = *(const bf16x8*)&wpH[wrow];
            #pragma unroll
            for (int bt = 0; bt < 2; ++bt)
                acc[at][bt] = mfma16(awH, btH[bt], acc[at][bt]);
            if constexpr (F32) {
                bf16x8 awL = *(const bf16x8*)&wpL[wrow];
                #pragma unroll
                for (int bt = 0; bt < 2; ++bt) {
                    acc[at][bt] = mfma16(awH, btL[bt], acc[at][bt]);
                    acc[at][bt] = mfma16(awL, btH[bt], acc[at][bt]);
                }
            }
        }
    }

    #pragma unroll
    for (int at = 0; at < 8; ++at) {
        const int c0 = at * 16 + 4 * g;
        float bp[4];
        #pragma unroll
        for (int rr = 0; rr < 4; ++rr) bp[rr] = ldel<F32>(b_proj, c0 + rr);
        #pragma unroll
        for (int bt = 0; bt < 2; ++bt) {
            const int n = tok0 + bt * 16 + c16;
            const size_t ob = (size_t)n * 128 + c0;
            if constexpr (F32) {
                const float4 zv = *(const float4*)((const float*)z + ob);
                float4 o;
                o.x = acc[at][bt][0] + bp[0] + zv.x;
                o.y = acc[at][bt][1] + bp[1] + zv.y;
                o.z = acc[at][bt][2] + bp[2] + zv.z;
                o.w = acc[at][bt][3] + bp[3] + zv.w;
                *(float4*)((float*)out + ob) = o;
            } else {
                const uint2 zu = *(const uint2*)((const ush*)z + ob);
                float v0 = acc[at][bt][0] + bp[0] + bflo(zu.x);
                float v1 = acc[at][bt][1] + bp[1] + bfhi(zu.x);
                float v2 = acc[at][bt][2] + bp[2] + bflo(zu.y);
                float v3 = acc[at][bt][3] + bp[3] + bfhi(zu.y);
                uint2 u;
                u.x = (unsigned int)f2bf(v0) | ((unsigned int)f2bf(v1) << 16);
                u.y = (unsigned int)f2bf(v2) | ((unsigned int)f2bf(v3) << 16);
                *(uint2*)((ush*)out + ob) = u;
            }
        }
    }
}

// ======================================================================
// ============   FALLBACK (ws too small): round-1 kernels   ============
// ======================================================================
template<bool F32>
__global__ __launch_bounds__(256) void attn_mfma(
    const void* __restrict__ z, const void* __restrict__ ln_g, const void* __restrict__ ln_b,
    const void* __restrict__ w_qkv, const void* __restrict__ b_qkv, void* __restrict__ out)
{
    if (sniff_is_f32((const unsigned int*)z) != F32) return;

    __shared__ __align__(16) unsigned char smem[53248];
    ush* znH  = (ush*)smem;
    ush* znL  = (ush*)(smem + 16384);
    ush* wtH  = (ush*)(smem + 32768);
    ush* wtL  = (ush*)(smem + 38912);
    float* biasm = (float*)(smem + 45056);
    ush* kHs  = znH;
    ush* kLs  = znL;
    ush* vtH  = (ush*)(smem + 32768);

    const int t    = threadIdx.x;
    const int lane = t & 63;
    const int w    = t >> 6;
    const int g    = lane >> 4;
    const int c16  = lane & 15;
    const int r    = blockIdx.x >> 2;
    const int h    = blockIdx.x & 3;
    ush* ps = (ush*)(smem + 49152) + (w << 9);

    if (t < 96) {
        int gc = ((t >> 5) << 7) + (h << 5) + (t & 31);
        float b0 = 0.f, b1 = 0.f;
        #pragma unroll 8
        for (int k = 0; k < 128; k += 2) {
            b0 += ldel<F32>(ln_b, k)     * ldel<F32>(w_qkv, k * 384 + gc);
            b1 += ldel<F32>(ln_b, k + 1) * ldel<F32>(w_qkv, (k + 1) * 384 + gc);
        }
        biasm[t] = ldel<F32>(b_qkv, gc) + b0 + b1;
    }

    const void* zrow = elptr<F32>(z, ((size_t)r * 256 + t) << 7);
    float sum = 0.f, sumsq = 0.f;
    #pragma unroll 1
    for (int i = 0; i < 16; ++i) {
        float v[8]; ld8<F32>(zrow, i, v);
        #pragma unroll
        for (int j = 0; j < 8; ++j) { sum += v[j]; sumsq += v[j] * v[j]; }
    }
    const float mu   = sum * (1.f / 128.f);
    const float rsig = 1.0f / sqrtf(sumsq * (1.f / 128.f) - mu * mu + 1e-5f);
    const float nb   = -mu * rsig;

    __syncthreads();

    float bv[6];
    #pragma unroll
    for (int ct = 0; ct < 6; ++ct) bv[ct] = biasm[ct * 16 + c16];

    f32x4 acc[4][6];
    #pragma unroll
    for (int qt = 0; qt < 4; ++qt)
        #pragma unroll
        for (int ct = 0; ct < 6; ++ct)
            #pragma unroll
            for (int rr = 0; rr < 4; ++rr) acc[qt][ct][rr] = 0.f;

    #pragma unroll 1
    for (int kc = 0; kc < 4; ++kc) {
        {
            float vv[8];
            #pragma unroll
            for (int i8 = 0; i8 < 4; ++i8) {
                ld8<F32>(zrow, kc * 4 + i8, vv);
                union { ush s[8]; uint4 v4; } uh, ul;
                #pragma unroll
                for (int j = 0; j < 8; ++j) {
                    float zh = fmaf(vv[j], rsig, nb);
                    splitf(zh, uh.s[j], ul.s[j]);
                }
                int b2 = sw_frag(t, i8);
                *(uint4*)&znH[b2] = uh.v4;
                *(uint4*)&znL[b2] = ul.v4;
            }
        }
        for (int idx = t; idx < 3072; idx += 256) {
            int c  = idx % 96;
            int kl = idx / 96;
            int kk = kc * 32 + kl;
            int gc = ((c >> 5) << 7) + (h << 5) + (c & 31);
            float wv = ldel<F32>(ln_g, kk) * ldel<F32>(w_qkv, kk * 384 + gc);
            ush hh, ll; splitf(wv, hh, ll);
            int o = sw_off(c, kl);
            wtH[o] = hh; wtL[o] = ll;
        }
        __syncthreads();

        bf16x8 bH[6], bL[6];
        #pragma unroll
        for (int ct = 0; ct < 6; ++ct) {
            int brow = ct * 16 + c16;
            bH[ct] = *(const bf16x8*)&wtH[sw_frag(brow, g)];
            bL[ct] = *(const bf16x8*)&wtL[sw_frag(brow, g)];
        }
        #pragma unroll
        for (int qt = 0; qt < 4; ++qt) {
            int arow = (w << 6) + (qt << 4) + c16;
            bf16x8 aHf = *(const bf16x8*)&znH[sw_frag(arow, g)];
            bf16x8 aLf = *(const bf16x8*)&znL[sw_frag(arow, g)];
            #pragma unroll
            for (int ct = 0; ct < 6; ++ct) {
                acc[qt][ct] = mfma16(aHf, bH[ct], acc[qt][ct]);
                acc[qt][ct] = mfma16(aHf, bL[ct], acc[qt][ct]);
                acc[qt][ct] = mfma16(aLf, bH[ct], acc[qt][ct]);
            }
        }
        __syncthreads();
    }

    #pragma unroll
    for (int qt = 0; qt < 4; ++qt)
        #pragma unroll
        for (int ct = 0; ct < 6; ++ct)
            #pragma unroll
            for (int rr = 0; rr < 4; ++rr) acc[qt][ct][rr] += bv[ct];

    #pragma unroll
    for (int qt = 0; qt < 4; ++qt) {
        #pragma unroll
        for (int rr = 0; rr < 4; ++rr) {
            int key = (w << 6) + (qt << 4) + 4 * g + rr;
            ush hh, ll;
            splitf(acc[qt][2][rr], hh, ll);
            kHs[sw_off(key, c16)]      = hh; kLs[sw_off(key, c16)]      = ll;
            splitf(acc[qt][3][rr], hh, ll);
            kHs[sw_off(key, 16 + c16)] = hh; kLs[sw_off(key, 16 + c16)] = ll;
            vtH[vt_off(c16,      key)] = f2bf(acc[qt][4][rr]);
            vtH[vt_off(16 + c16, key)] = f2bf(acc[qt][5][rr]);
        }
    }

    const float SCALE = 0.17677669529663689f;
    bf16x8 qfH[4], qfL[4];
    #pragma unroll
    for (int qt = 0; qt < 4; ++qt) {
        #pragma unroll
        for (int rr = 0; rr < 4; ++rr) {
            int rw = 4 * g + rr;
            ps[sw_off(rw, c16)]      = f2bf(acc[qt][0][rr] * SCALE);
            ps[sw_off(rw, 16 + c16)] = f2bf(acc[qt][1][rr] * SCALE);
        }
        qfH[qt] = *(const bf16x8*)&ps[sw_frag(c16, g)];
        #pragma unroll
        for (int rr = 0; rr < 4; ++rr) {
            int rw = 4 * g + rr;
            float q0 = acc[qt][0][rr] * SCALE;
            float q1 = acc[qt][1][rr] * SCALE;
            ps[sw_off(rw, c16)]      = f2bf(q0 - bf2f(f2bf(q0)));
            ps[sw_off(rw, 16 + c16)] = f2bf(q1 - bf2f(f2bf(q1)));
        }
        qfL[qt] = *(const bf16x8*)&ps[sw_frag(c16, g)];
    }
    __syncthreads();

    float m[16], l[16];
    #pragma unroll
    for (int i = 0; i < 16; ++i) { m[i] = -3.0e38f; l[i] = 0.f; }
    f32x4 O[4][2];
    #pragma unroll
    for (int qt = 0; qt < 4; ++qt)
        #pragma unroll
        for (int dt = 0; dt < 2; ++dt)
            #pragma unroll
            for (int rr = 0; rr < 4; ++rr) O[qt][dt][rr] = 0.f;

    f32x4 zed; zed[0] = 0.f; zed[1] = 0.f; zed[2] = 0.f; zed[3] = 0.f;

    #pragma unroll 1
    for (int kb = 0; kb < 8; ++kb) {
        int key0 = kb * 32;
        bf16x8 kfH[2], kfL[2], vf[2];
        #pragma unroll
        for (int kt = 0; kt < 2; ++kt) {
            int krow = key0 + 16 * kt + c16;
            kfH[kt] = *(const bf16x8*)&kHs[sw_frag(krow, g)];
            kfL[kt] = *(const bf16x8*)&kLs[sw_frag(krow, g)];
        }
        #pragma unroll
        for (int dt = 0; dt < 2; ++dt)
            vf[dt] = *(const bf16x8*)&vtH[vt_off(16 * dt + c16, key0 + 8 * g)];

        #pragma unroll
        for (int qt = 0; qt < 4; ++qt) {
            f32x4 s0 = mfma16(qfH[qt], kfH[0], zed);
            s0 = mfma16(qfH[qt], kfL[0], s0);
            s0 = mfma16(qfL[qt], kfH[0], s0);
            f32x4 s1 = mfma16(qfH[qt], kfH[1], zed);
            s1 = mfma16(qfH[qt], kfL[1], s1);
            s1 = mfma16(qfL[qt], kfH[1], s1);

            #pragma unroll
            for (int rr = 0; rr < 4; ++rr) {
                float mx = fmaxf(s0[rr], s1[rr]);
                mx = fmaxf(mx, __shfl_xor(mx, 1));
                mx = fmaxf(mx, __shfl_xor(mx, 2));
                mx = fmaxf(mx, __shfl_xor(mx, 4));
                mx = fmaxf(mx, __shfl_xor(mx, 8));
                const int idx = qt * 4 + rr;
                float mo = m[idx];
                float mn = fmaxf(mo, mx);
                float al = __expf(fmaxf(mo - mn, -87.f));
                float p0 = __expf(s0[rr] - mn);
                float p1 = __expf(s1[rr] - mn);
                l[idx] = l[idx] * al + p0 + p1;
                m[idx] = mn;
                O[qt][0][rr] *= al;
                O[qt][1][rr] *= al;
                int rw = 4 * g + rr;
                ps[sw_off(rw, c16)]      = f2bf(p0);
                ps[sw_off(rw, 16 + c16)] = f2bf(p1);
            }
            bf16x8 pf = *(const bf16x8*)&ps[sw_frag(c16, g)];
            O[qt][0] = mfma16(pf, vf[0], O[qt][0]);
            O[qt][1] = mfma16(pf, vf[1], O[qt][1]);
        }
    }

    #pragma unroll
    for (int i = 0; i < 16; ++i) {
        float s = l[i];
        s += __shfl_xor(s, 1);
        s += __shfl_xor(s, 2);
        s += __shfl_xor(s, 4);
        s += __shfl_xor(s, 8);
        l[i] = s;
    }

    #pragma unroll
    for (int qt = 0; qt < 4; ++qt) {
        #pragma unroll
        for (int rr = 0; rr < 4; ++rr) {
            float rlv = 1.f / l[qt * 4 + rr];
            int grow = (r << 8) + (w << 6) + (qt << 4) + 4 * g + rr;
            size_t base = ((size_t)grow << 7) + (h << 5);
            if constexpr (F32) {
                float* po = (float*)out + base;
                po[c16]      = O[qt][0][rr] * rlv;
                po[16 + c16] = O[qt][1][rr] * rlv;
            } else {
                ush* po = (ush*)out + base;
                po[c16]      = f2bf(O[qt][0][rr] * rlv);
                po[16 + c16] = f2bf(O[qt][1][rr] * rlv);
            }
        }
    }
}

template<bool F32>
__global__ __launch_bounds__(256) void proj_res(
    const void* __restrict__ z, const void* __restrict__ w_proj, const void* __restrict__ b_proj,
    void* __restrict__ out)
{
    if (sniff_is_f32((const unsigned int*)z) != F32) return;

    __shared__ unsigned int wu[8192];
    __shared__ float aT[128][20];

    const int t = threadIdx.x;
    const size_t row0 = (size_t)blockIdx.x * 16;

    if constexpr (!F32) {
        for (int idx = t; idx < 8192; idx += 256)
            wu[idx] = ((const unsigned int*)w_proj)[idx];
    }

    {
        const int rr = t >> 4;
        const int i8 = t & 15;
        float v[8];
        ld8<F32>(elptr<F32>((const void*)out, (row0 + rr) * 128), i8, v);
        #pragma unroll
        for (int j = 0; j < 8; ++j) aT[(i8 << 3) + j][rr] = v[j];
    }
    __syncthreads();

    const int c = t & 127;
    const int half = t >> 7;
    float acc8[8];
    const float bp = ldel<F32>(b_proj, c);
    #pragma unroll
    for (int rr = 0; rr < 8; ++rr) acc8[rr] = bp;

    #pragma unroll 1
    for (int k = 0; k < 128; ++k) {
        float wk;
        if constexpr (F32) {
            wk = ((const float*)w_proj)[k * 128 + c];
        } else {
            unsigned int u = wu[(k << 6) + (c >> 1)];
            wk = (c & 1) ? bfhi(u) : bflo(u);
        }
        const float4 a0 = *(const float4*)&aT[k][half * 8];
        const float4 a1 = *(const float4*)&aT[k][half * 8 + 4];
        acc8[0] = fmaf(a0.x, wk, acc8[0]);
        acc8[1] = fmaf(a0.y, wk, acc8[1]);
        acc8[2] = fmaf(a0.z, wk, acc8[2]);
        acc8[3] = fmaf(a0.w, wk, acc8[3]);
        acc8[4] = fmaf(a1.x, wk, acc8[4]);
        acc8[5] = fmaf(a1.y, wk, acc8[5]);
        acc8[6] = fmaf(a1.z, wk, acc8[6]);
        acc8[7] = fmaf(a1.w, wk, acc8[7]);
    }
    __syncthreads();
    float* ot = (float*)aT;
    #pragma unroll
    for (int rr = 0; rr < 8; ++rr)
        ot[(half * 8 + rr) * 128 + c] = acc8[rr];
    __syncthreads();

    {
        const int rr = t >> 4;
        const int i8 = t & 15;
        float zv[8], v[8];
        ld8<F32>(elptr<F32>(z, (row0 + rr) * 128), i8, zv);
        const float* po = &ot[rr * 128 + (i8 << 3)];
        #pragma unroll
        for (int j = 0; j < 8; ++j) v[j] = po[j] + zv[j];
        st8<F32>(elptrw<F32>(out, (row0 + rr) * 128), i8, v);
    }
}

extern "C" void kernel_launch(void* const* d_in, const int* in_sizes, int n_in,
                              void* d_out, int out_size, void* d_ws, size_t ws_size,
                              hipStream_t stream) {
    const void* z      = d_in[0];
    const void* ln_g   = d_in[1];
    const void* ln_b   = d_in[2];
    const void* w_qkv  = d_in[3];
    const void* b_qkv  = d_in[4];
    const void* w_proj = d_in[5];
    const void* b_proj = d_in[6];
    void* out = d_out;

    if (ws_size >= WS_NEED && d_ws != nullptr) {
        unsigned char* W = (unsigned char*)d_ws;
        ush*   wqSH  = (ush*)(W + 0);
        ush*   wqSL  = (ush*)(W + 98304);
        ush*   wpH   = (ush*)(W + 196608);
        ush*   wpL   = (ush*)(W + 229376);
        float* biasG = (float*)(W + 262144);

        prep_w<false><<<64, 256, 0, stream>>>(z, ln_g, ln_b, w_qkv, b_qkv, w_proj, wqSH, wqSL, wpH, wpL, biasG);
        prep_w<true ><<<64, 256, 0, stream>>>(z, ln_g, ln_b, w_qkv, b_qkv, w_proj, wqSH, wqSL, wpH, wpL, biasG);
        attn_mfma2<false><<<1024, 256, 0, stream>>>(z, wqSH, wqSL, biasG, out);
        attn_mfma2<true ><<<1024, 256, 0, stream>>>(z, wqSH, wqSL, biasG, out);
        proj_mfma2<false><<<512, 256, 0, stream>>>(z, b_proj, wpH, wpL, out);
        proj_mfma2<true ><<<512, 256, 0, stream>>>(z, b_proj, wpH, wpL, out);
    } else {
        attn_mfma<false><<<1024, 256, 0, stream>>>(z, ln_g, ln_b, w_qkv, b_qkv, out);
        attn_mfma<true ><<<1024, 256, 0, stream>>>(z, ln_g, ln_b, w_qkv, b_qkv, out);
        proj_res<false><<<4096, 256, 0, stream>>>(z, w_proj, b_proj, out);
        proj_res<true ><<<4096, 256, 0, stream>>>(z, w_proj, b_proj, out);
    }
}